// Round 1
// baseline (168.237 us; speedup 1.0000x reference)
//
#include <hip/hip_runtime.h>

// Shape-matching constraint projection.
// Key simplification: the reference's rot = Vh^T @ (Vh with last row * det(Vh^T Vh))
// == Identity up to SVD orthogonality noise (~1e-6). U and s from the SVD are
// discarded. So delta_x = init - (pred - com), no SVD needed.
//
// delta_pos = (V_w / V_compliance) * (init - pred + com)
// out[idx]  = V_predict[idx] + delta_pos
// L_last is passed through unchanged.
//
// Parallelization: 16 lanes per constraint (P=16), 4 constraints per wave.
// com reduction via __shfl_xor within 16-lane groups. All loads/stores
// coalesced (C_shape is arange -> contiguous).

#define P_PART 16

__global__ __launch_bounds__(256) void shape_match_kernel(
    const float* __restrict__ V_predict,
    const float* __restrict__ V_w,
    const float* __restrict__ V_mass,
    const int*   __restrict__ C_shape,
    const float* __restrict__ C_init,
    const float* __restrict__ V_comp,
    float*       __restrict__ out,
    int num_c)
{
    int t = blockIdx.x * blockDim.x + threadIdx.x;
    int c = t >> 4;          // constraint id
    if (c >= num_c) return;
    int gp = t;              // global particle slot = c*16 + p

    int idx = C_shape[gp];

    const float3 pred = *reinterpret_cast<const float3*>(V_predict + (size_t)idx * 3);
    const float3 init = *reinterpret_cast<const float3*>(C_init    + (size_t)gp  * 3);
    const float m    = V_mass[idx];
    const float w    = V_w[idx];
    const float comp = V_comp[idx];

    // weighted center of mass over the 16-lane group
    float sx = m * pred.x;
    float sy = m * pred.y;
    float sz = m * pred.z;
    float sm = m;
    #pragma unroll
    for (int off = 8; off >= 1; off >>= 1) {
        sx += __shfl_xor(sx, off, P_PART);
        sy += __shfl_xor(sy, off, P_PART);
        sz += __shfl_xor(sz, off, P_PART);
        sm += __shfl_xor(sm, off, P_PART);
    }
    const float inv = 1.0f / sm;
    const float comx = sx * inv;
    const float comy = sy * inv;
    const float comz = sz * inv;

    // delta_pos = w * (init - (pred - com)) * (1/comp)
    const float stiff = 1.0f / comp;
    float3 o;
    o.x = pred.x + w * (init.x - (pred.x - comx)) * stiff;
    o.y = pred.y + w * (init.y - (pred.y - comy)) * stiff;
    o.z = pred.z + w * (init.z - (pred.z - comz)) * stiff;

    *reinterpret_cast<float3*>(out + (size_t)idx * 3) = o;
}

extern "C" void kernel_launch(void* const* d_in, const int* in_sizes, int n_in,
                              void* d_out, int out_size, void* d_ws, size_t ws_size,
                              hipStream_t stream)
{
    const float* V_predict = (const float*)d_in[0];
    const float* L_last    = (const float*)d_in[1];
    const float* V_w       = (const float*)d_in[2];
    const float* V_mass    = (const float*)d_in[3];
    const int*   C_shape   = (const int*)  d_in[4];
    const float* C_init    = (const float*)d_in[5];
    const float* V_comp    = (const float*)d_in[6];

    const int N     = in_sizes[0] / 3;   // vertices
    const int num_c = in_sizes[1];       // constraints
    // P is fixed at 16 (shfl width assumption)

    float* out = (float*)d_out;

    const int total_particles = num_c * P_PART;
    const int block = 256;
    const int grid  = (total_particles + block - 1) / block;

    shape_match_kernel<<<grid, block, 0, stream>>>(
        V_predict, V_w, V_mass, C_shape, C_init, V_comp, out, num_c);

    // L_last passthrough -> second output, concatenated after V_predict_new
    hipMemcpyAsync(out + (size_t)N * 3, L_last, (size_t)num_c * sizeof(float),
                   hipMemcpyDeviceToDevice, stream);
}